// Round 2
// baseline (2645.681 us; speedup 1.0000x reference)
//
#include <hip/hip_runtime.h>
#include <math.h>

#define VOCAB 50000
#define EMB 256
#define HID 512
#define G4 2048   // 4*HID
#define KTAGS 20
#define START_TAG 18
#define END_TAG 19
#define BB 32
#define TT 256
#define NEGV -10000.0f
#define HSROW 644   // 640 phys floats per row + 4 skew
#define XSROW 264   // 256 + 8 skew
#define SLOTF 32768      // floats per hping slot: 2 dir * 32 * 512
#define SLOTBYTES 131072

__device__ __forceinline__ float sigmoidf_(float x) { return 1.0f / (1.0f + expf(-x)); }

// ---------------------------------------------------------------------------
// K2: persistent batched LSTM, dual-dir merged phases + FUSED input GEMM.
//   256 WGs x 512 thr (1/CU). WG = (8-unit slice, 8-batch sorted group).
//
//   r17 CHANGE: counter barrier -> SENTINEL DATAFLOW exchange.
//   hping is a 3-deep rotating buffer [3 slot][2 dir][32][512]:
//     step t: READ slot t%3 (poll the data: NaN = not written yet),
//             RESET slot (t+2)%3 to NaN (cells this WG owns; drained by the
//             staging barrier before this WG's next h-store is issued),
//             WRITE h(t+1) into slot (t+1)%3.
//   Slot0 memset 0.0 (= valid h(0)); slots 1,2 memset 0xFF (NaN sentinel).
//   h in (-1,1) can never be NaN, so "all 4 floats ordered" == chunk ready.
//   This merges barrier-observe + h-load into ONE LLC access, deletes the
//   arrive RMWs and the 16-line counter poll storm, and turns the hard
//   per-step barrier into self-timed slack (skew pipelines across steps).
//   emb gather is prefetched one step ahead (tokens known in advance).
// ---------------------------------------------------------------------------
__global__ __launch_bounds__(512, 1) void k_lstm_persist(
    const int* __restrict__ lengths,
    const int* __restrict__ sentence,  // [32][256]
    const float* __restrict__ emb,     // [VOCAB][256]
    const float* __restrict__ Wf_hh, const float* __restrict__ Wb_hh,
    const float* __restrict__ Wf_ih, const float* __restrict__ Wb_ih,
    const float* __restrict__ bf_ih, const float* __restrict__ bf_hh,
    const float* __restrict__ bb_ih, const float* __restrict__ bb_hh,
    float* __restrict__ hping,         // [3 slot][2 dir][32][512]
    float* __restrict__ hbuf)          // [2][32][256][512]
{
    const int wg = blockIdx.x;             // 0..255
    const int slice = wg >> 2;             // unit slice 0..63
    const int grp = wg & 3;                // sorted batch group 0..3
    const int tid = threadIdx.x;
    const int wave = tid >> 6;             // 0..7 = local unit
    const int lane = tid & 63;             // k-slice
    const int u_glob = slice * 8 + wave;   // 0..511

    // recurrent weights: 8 h-floats per lane per gate per dir
    float4 wF[4][2], wB[4][2];
    #pragma unroll
    for (int c = 0; c < 4; c++) {
        const float4* wr = (const float4*)(Wf_hh + (size_t)(c * HID + u_glob) * HID + lane * 8);
        wF[c][0] = wr[0]; wF[c][1] = wr[1];
        const float4* wr2 = (const float4*)(Wb_hh + (size_t)(c * HID + u_glob) * HID + lane * 8);
        wB[c][0] = wr2[0]; wB[c][1] = wr2[1];
    }
    // input weights: 4 x-floats per lane per gate per dir
    float4 iF[4], iB[4];
    #pragma unroll
    for (int c = 0; c < 4; c++) {
        iF[c] = *(const float4*)(Wf_ih + (size_t)(c * HID + u_glob) * EMB + lane * 4);
        iB[c] = *(const float4*)(Wb_ih + (size_t)(c * HID + u_glob) * EMB + lane * 4);
    }
    // biases for this wave's unit
    float bFc[4], bBc[4];
    #pragma unroll
    for (int c = 0; c < 4; c++) {
        bFc[c] = bf_ih[c * HID + u_glob] + bf_hh[c * HID + u_glob];
        bBc[c] = bb_ih[c * HID + u_glob] + bb_hh[c * HID + u_glob];
    }

    __shared__ float hs[16 * HSROW];       // rows 0-7: F h, 8-15: B h
    __shared__ float xs[16 * XSROW];       // rows 0-7: F x, 8-15: B x
    __shared__ float zw[16 * 132];         // [dir*8+wave][gate*33 + j]
    __shared__ int stok[8][TT];            // tokens for group's 8 sorted batches
    __shared__ int lens_raw[32];
    __shared__ int order_s[32];
    __shared__ int lens_s[32];
    __shared__ int nbt_s[TT];

    if (tid < 32) lens_raw[tid] = lengths[tid];
    __syncthreads();
    if (tid < 32) {
        int me = lens_raw[tid], rank = 0;
        #pragma unroll 4
        for (int o = 0; o < 32; o++) {
            int lo = lens_raw[o];
            rank += (lo > me || (lo == me && o < tid)) ? 1 : 0;
        }
        order_s[rank] = tid;
        lens_s[rank] = me;
    }
    if (tid >= 256) {
        int t = tid - 256, c = 0;
        #pragma unroll 4
        for (int b = 0; b < 32; b++) c += (lens_raw[b] > t) ? 1 : 0;
        nbt_s[t] = c;
    }
    __syncthreads();
    for (int i = tid; i < 8 * TT; i += 512) {
        int j = i >> 8, c = i & 255;
        stok[j][c] = sentence[order_s[grp * 8 + j] * TT + c];
    }
    __syncthreads();

    const int tlimit = lens_s[grp * 8];

    // gate identity: lanes 0..7 = local sorted pos within group
    const int gj = lane & 7;
    const int g_act = (lane < 8);
    const int p_sort = grp * 8 + gj;
    const int mylen = lens_s[p_sort];
    const int mybat = order_s[p_sort];
    float* houtF = hbuf + (size_t)mybat * TT * HID + u_glob;
    float* houtB = hbuf + (size_t)(BB + mybat) * TT * HID + u_glob;
    float* hpF = hping + (size_t)mybat * HID + u_glob;            // slot-0 base
    float* hpB = hping + (size_t)(BB + mybat) * HID + u_glob;     // slot-0 base

    // h staging: 4 slots/thread. kq = tid&127, rA = tid>>7 (0..3)
    const int kq = tid & 127;
    const int rA = tid >> 7;
    const int wbBase = 4 * kq + 4 * (kq >> 2);
    const int sb_lo = order_s[grp * 8 + rA];
    const int sb_hi = order_s[grp * 8 + rA + 4];
    const int sb0   = order_s[grp * 8];   // longest batch in group: always live
    const size_t o_lo = (size_t)sb_lo * 2048 + (size_t)kq * 16;
    const size_t o_hi = (size_t)sb_hi * 2048 + (size_t)kq * 16;
    const size_t o_fb = (size_t)sb0   * 2048 + (size_t)kq * 16;

    // x staging: row16 = tid>>5 (0..15), part = tid&31 (8 floats each)
    const int xrow = tid >> 5;
    const int xpart = tid & 31;
    const int xjrow = xrow & 7;
    const int xlen = lens_s[grp * 8 + xjrow];
    const bool xisB = xrow >= 8;
    float* xdst = &xs[xrow * XSROW + xpart * 8];

    const int rdoff = 8 * lane + 4 * (lane >> 1);

    float cF = 0.f, cB = 0.f;
    const float SENTN = __uint_as_float(0xFFFFFFFFu);

    // prologue: load x(0) into regs (consumed at staging of step 0)
    float4 xa, xb2;
    {
        int posx = xisB ? (xlen - 1) : 0;   // xlen >= 1 always
        const float* xr = emb + (size_t)stok[xjrow][posx] * EMB + xpart * 8;
        xa  = *(const float4*)xr;
        xb2 = *(const float4*)(xr + 4);
    }

#define DOTRED(WREG, WIH, ROWOFF, ZOFF)                                        \
    for (int j = 0; j < jmax; j++) {                                           \
        const float* hb = &hs[((ROWOFF) + j) * HSROW + rdoff];                 \
        float4 h0 = *(const float4*)(hb);                                      \
        float4 h1 = *(const float4*)(hb + 4);                                  \
        float4 xv = *(const float4*)&xs[((ROWOFF) + j) * XSROW + lane * 4];    \
        float a0 = 0.f, a1 = 0.f, a2 = 0.f, a3 = 0.f;                          \
        a0 = fmaf(WREG[0][0].x, h0.x, a0); a0 = fmaf(WREG[0][0].y, h0.y, a0);  \
        a0 = fmaf(WREG[0][0].z, h0.z, a0); a0 = fmaf(WREG[0][0].w, h0.w, a0);  \
        a0 = fmaf(WREG[0][1].x, h1.x, a0); a0 = fmaf(WREG[0][1].y, h1.y, a0);  \
        a0 = fmaf(WREG[0][1].z, h1.z, a0); a0 = fmaf(WREG[0][1].w, h1.w, a0);  \
        a0 = fmaf(WIH[0].x, xv.x, a0);     a0 = fmaf(WIH[0].y, xv.y, a0);      \
        a0 = fmaf(WIH[0].z, xv.z, a0);     a0 = fmaf(WIH[0].w, xv.w, a0);      \
        a1 = fmaf(WREG[1][0].x, h0.x, a1); a1 = fmaf(WREG[1][0].y, h0.y, a1);  \
        a1 = fmaf(WREG[1][0].z, h0.z, a1); a1 = fmaf(WREG[1][0].w, h0.w, a1);  \
        a1 = fmaf(WREG[1][1].x, h1.x, a1); a1 = fmaf(WREG[1][1].y, h1.y, a1);  \
        a1 = fmaf(WREG[1][1].z, h1.z, a1); a1 = fmaf(WREG[1][1].w, h1.w, a1);  \
        a1 = fmaf(WIH[1].x, xv.x, a1);     a1 = fmaf(WIH[1].y, xv.y, a1);      \
        a1 = fmaf(WIH[1].z, xv.z, a1);     a1 = fmaf(WIH[1].w, xv.w, a1);      \
        a2 = fmaf(WREG[2][0].x, h0.x, a2); a2 = fmaf(WREG[2][0].y, h0.y, a2);  \
        a2 = fmaf(WREG[2][0].z, h0.z, a2); a2 = fmaf(WREG[2][0].w, h0.w, a2);  \
        a2 = fmaf(WREG[2][1].x, h1.x, a2); a2 = fmaf(WREG[2][1].y, h1.y, a2);  \
        a2 = fmaf(WREG[2][1].z, h1.z, a2); a2 = fmaf(WREG[2][1].w, h1.w, a2);  \
        a2 = fmaf(WIH[2].x, xv.x, a2);     a2 = fmaf(WIH[2].y, xv.y, a2);      \
        a2 = fmaf(WIH[2].z, xv.z, a2);     a2 = fmaf(WIH[2].w, xv.w, a2);      \
        a3 = fmaf(WREG[3][0].x, h0.x, a3); a3 = fmaf(WREG[3][0].y, h0.y, a3);  \
        a3 = fmaf(WREG[3][0].z, h0.z, a3); a3 = fmaf(WREG[3][0].w, h0.w, a3);  \
        a3 = fmaf(WREG[3][1].x, h1.x, a3); a3 = fmaf(WREG[3][1].y, h1.y, a3);  \
        a3 = fmaf(WREG[3][1].z, h1.z, a3); a3 = fmaf(WREG[3][1].w, h1.w, a3);  \
        a3 = fmaf(WIH[3].x, xv.x, a3);     a3 = fmaf(WIH[3].y, xv.y, a3);      \
        a3 = fmaf(WIH[3].z, xv.z, a3);     a3 = fmaf(WIH[3].w, xv.w, a3);      \
        bool lo32 = (lane & 32) == 0;                                          \
        float tA = __shfl_xor(lo32 ? a2 : a0, 32);                             \
        float tB = __shfl_xor(lo32 ? a3 : a1, 32);                             \
        float rAq = (lo32 ? a0 : a2) + tA;                                     \
        float rBq = (lo32 ? a1 : a3) + tB;                                     \
        bool lo16 = (lane & 16) == 0;                                          \
        float tC = __shfl_xor(lo16 ? rBq : rAq, 16);                           \
        float r  = (lo16 ? rAq : rBq) + tC;                                    \
        r += __shfl_xor(r, 8);                                                 \
        r += __shfl_xor(r, 4);                                                 \
        r += __shfl_xor(r, 2);                                                 \
        r += __shfl_xor(r, 1);                                                 \
        if ((lane & 15) == 0)                                                  \
            zw[((ZOFF) + wave) * 132 + (lane >> 4) * 33 + j] = r;              \
    }

#define PLOAD(U, A)                                                            \
    asm volatile("global_load_dwordx4 %0, %1, off sc0 sc1"                     \
                 : "=&v"(U) : "v"(A) : "memory")

    int slotR = 0, slotW = 1, slotZ = 2;

    for (int t = 0; t < tlimit; t++) {
        const int nbt = nbt_s[t];
        const int jmax = min(max(nbt - grp * 8, 0), 8);
        const int act = g_act && (t < mylen);
        const int pred_lo = (grp * 8 + rA < nbt);
        const int pred_hi = (grp * 8 + rA + 4 < nbt);

        // ---- issue x(t+1) prefetch (lands during the poll's vmcnt wait) ----
        float4 xna, xnb;
        {
            int tp = (t + 1 < tlimit) ? t + 1 : t;
            int posn = xisB ? ((tp < xlen) ? xlen - 1 - tp : tp) : tp;
            const float* xrn = emb + (size_t)stok[xjrow][posn] * EMB + xpart * 8;
            xna = *(const float4*)xrn;
            xnb = *(const float4*)(xrn + 4);
        }

        // ---- poll-load h(t): the load IS the barrier observe ----
        float4 u0, u1, u2, u3;
        {
            const char* baseF = (const char*)hping + (size_t)slotR * SLOTBYTES;
            const char* baseB = baseF + (SLOTBYTES / 2);
            const char* a0 = pred_lo ? baseF + o_lo : baseF + o_fb;
            const char* a1 = pred_hi ? baseF + o_hi : baseF + o_fb;
            const char* a2 = pred_lo ? baseB + o_lo : baseF + o_fb;
            const char* a3 = pred_hi ? baseB + o_hi : baseF + o_fb;
            asm volatile(
                "global_load_dwordx4 %0, %4, off sc0 sc1\n\t"
                "global_load_dwordx4 %1, %5, off sc0 sc1\n\t"
                "global_load_dwordx4 %2, %6, off sc0 sc1\n\t"
                "global_load_dwordx4 %3, %7, off sc0 sc1\n\t"
                "s_waitcnt vmcnt(0)"
                : "=&v"(u0), "=&v"(u1), "=&v"(u2), "=&v"(u3)
                : "v"(a0), "v"(a1), "v"(a2), "v"(a3)
                : "memory");
            while (true) {
                bool o0 = (u0.x == u0.x) & (u0.y == u0.y) & (u0.z == u0.z) & (u0.w == u0.w);
                bool o1 = (u1.x == u1.x) & (u1.y == u1.y) & (u1.z == u1.z) & (u1.w == u1.w);
                bool o2 = (u2.x == u2.x) & (u2.y == u2.y) & (u2.z == u2.z) & (u2.w == u2.w);
                bool o3 = (u3.x == u3.x) & (u3.y == u3.y) & (u3.z == u3.z) & (u3.w == u3.w);
                if (__ballot(!(o0 & o1 & o2 & o3)) == 0ull) break;
                if (!o0) PLOAD(u0, a0);
                if (!o1) PLOAD(u1, a1);
                if (!o2) PLOAD(u2, a2);
                if (!o3) PLOAD(u3, a3);
                asm volatile("s_waitcnt vmcnt(0)" ::: "memory");
            }
        }

        // ---- NaN-reset slot (t+2)%3 cells we own; drained by next barrier
        //      BEFORE this step's h-store is issued (visibility ordering) ----
        if (act) {
            __hip_atomic_store(hpF + (size_t)slotZ * SLOTF, SENTN,
                               __ATOMIC_RELAXED, __HIP_MEMORY_SCOPE_AGENT);
            __hip_atomic_store(hpB + (size_t)slotZ * SLOTF, SENTN,
                               __ATOMIC_RELAXED, __HIP_MEMORY_SCOPE_AGENT);
        }

        // all waves done with previous DOTRED's LDS reads before overwrite
        __syncthreads();

        // ---- stage h(t) + x(t) into LDS ----
        *(float4*)&hs[(rA     ) * HSROW + wbBase] = u0;
        *(float4*)&hs[(rA +  4) * HSROW + wbBase] = u1;
        *(float4*)&hs[(rA +  8) * HSROW + wbBase] = u2;
        *(float4*)&hs[(rA + 12) * HSROW + wbBase] = u3;
        *(float4*)xdst = xa;
        *(float4*)(xdst + 4) = xb2;
        __syncthreads();

        // ---- dots: F then B (Whh.h + Wih.x fused) ----
        DOTRED(wF, iF, 0, 0);
        DOTRED(wB, iB, 8, 8);

        // ---- gates: both dirs; h(t+1) -> slot (t+1)%3; history stores ----
        if (act) {
            {
                float iv = zw[wave * 132 +  0 + gj] + bFc[0];
                float fv = zw[wave * 132 + 33 + gj] + bFc[1];
                float gv = zw[wave * 132 + 66 + gj] + bFc[2];
                float ov = zw[wave * 132 + 99 + gj] + bFc[3];
                float cn = sigmoidf_(fv) * cF + sigmoidf_(iv) * tanhf(gv);
                float hn = sigmoidf_(ov) * tanhf(cn);
                cF = cn;
                __hip_atomic_store(hpF + (size_t)slotW * SLOTF, hn,
                                   __ATOMIC_RELAXED, __HIP_MEMORY_SCOPE_AGENT);
                houtF[(size_t)t * HID] = hn;
            }
            {
                float iv = zw[(8 + wave) * 132 +  0 + gj] + bBc[0];
                float fv = zw[(8 + wave) * 132 + 33 + gj] + bBc[1];
                float gv = zw[(8 + wave) * 132 + 66 + gj] + bBc[2];
                float ov = zw[(8 + wave) * 132 + 99 + gj] + bBc[3];
                float cn = sigmoidf_(fv) * cB + sigmoidf_(iv) * tanhf(gv);
                float hn = sigmoidf_(ov) * tanhf(cn);
                cB = cn;
                __hip_atomic_store(hpB + (size_t)slotW * SLOTF, hn,
                                   __ATOMIC_RELAXED, __HIP_MEMORY_SCOPE_AGENT);
                houtB[(size_t)t * HID] = hn;
            }
        }

        // ---- rotate slots, advance x pipeline ----
        int tmp = slotR; slotR = slotW; slotW = slotZ; slotZ = tmp;
        xa = xna; xb2 = xnb;
    }
#undef DOTRED
#undef PLOAD
}

// ---------------------------------------------------------------------------
// K3: feats — one wave per (b,t), all 64 lanes, LDS transpose-reduce.
// ---------------------------------------------------------------------------
__global__ __launch_bounds__(256) void k_feats(
    const int* __restrict__ lengths,
    const float* __restrict__ hbuf,  // [2][B][T][512]
    const float* __restrict__ Wout,  // [20][1024]
    const float* __restrict__ bout,  // [20]
    float* __restrict__ feats)       // [B][T][20]
{
    const int w = threadIdx.x >> 6;
    const int lane = threadIdx.x & 63;
    const int idx = blockIdx.x * 4 + w;
    const int b = idx >> 8, t = idx & 255;
    const int len = lengths[b];

    __shared__ float red[4][64][21];

    float acc[KTAGS];
    bool active = (t < len);
    if (active) {
        const int ofs = lane * 16;
        const float* src = (ofs < HID)
            ? hbuf + ((size_t)b * TT + t) * HID + ofs
            : hbuf + ((size_t)(BB + b) * TT + (len - 1 - t)) * HID + (ofs - HID);
        float x[16];
        #pragma unroll
        for (int q = 0; q < 4; q++) {
            float4 v = *(const float4*)(src + 4 * q);
            x[4 * q] = v.x; x[4 * q + 1] = v.y; x[4 * q + 2] = v.z; x[4 * q + 3] = v.w;
        }
        #pragma unroll
        for (int k = 0; k < KTAGS; k++) {
            const float* wr = Wout + (size_t)k * (2 * HID) + ofs;
            float a = 0.f;
            #pragma unroll
            for (int q = 0; q < 4; q++) {
                float4 v = *(const float4*)(wr + 4 * q);
                a = fmaf(x[4 * q], v.x, a);
                a = fmaf(x[4 * q + 1], v.y, a);
                a = fmaf(x[4 * q + 2], v.z, a);
                a = fmaf(x[4 * q + 3], v.w, a);
            }
            acc[k] = a;
        }
    } else {
        #pragma unroll
        for (int k = 0; k < KTAGS; k++) acc[k] = 0.f;
    }
    #pragma unroll
    for (int k = 0; k < KTAGS; k++) red[w][lane][k] = acc[k];
    __syncthreads();

    if (active && lane < KTAGS) {
        float s = bout[lane];
        #pragma unroll 8
        for (int l = 0; l < 64; l++) s += red[w][l][lane];
        feats[(size_t)idx * KTAGS + lane] = s;
    }
}

// ---------------------------------------------------------------------------
// K4: Viterbi — LDS backpointers, double-buffered fv, feats prefetch.
// ---------------------------------------------------------------------------
__global__ __launch_bounds__(64) void k_viterbi(
    const int* __restrict__ lengths,
    const float* __restrict__ trans,  // [20][20]
    const float* __restrict__ feats,  // [B][T][20]
    float* __restrict__ out)          // [32 scores][32*257 path]
{
    const int b = blockIdx.x;
    const int len = lengths[b];
    const int tid = threadIdx.x;

    __shared__ float tr[KTAGS * KTAGS];
    __shared__ float fvb[2][KTAGS];
    __shared__ int   bp[TT][KTAGS];
    __shared__ float term[KTAGS];

    for (int i = tid; i < KTAGS * KTAGS; i += 64) tr[i] = trans[i];
    if (tid < KTAGS) fvb[0][tid] = (tid == START_TAG) ? 0.f : NEGV;
    __syncthreads();

    float ft = (tid < KTAGS) ? feats[((size_t)b * TT) * KTAGS + tid] : 0.f;
    for (int t = 0; t < len; t++) {
        float ftn = (tid < KTAGS && t + 1 < len)
                  ? feats[((size_t)b * TT + t + 1) * KTAGS + tid] : 0.f;
        if (tid < KTAGS) {
            const float* fvc = fvb[t & 1];
            float best = -1e30f; int bi = 0;
            #pragma unroll
            for (int p = 0; p < KTAGS; p++) {
                float s = fvc[p] + tr[tid * KTAGS + p];
                if (s > best) { best = s; bi = p; }
            }
            fvb[(t + 1) & 1][tid] = best + ft;
            bp[t][tid] = bi;
        }
        ft = ftn;
        __syncthreads();
    }

    if (tid < KTAGS) term[tid] = fvb[len & 1][tid] + tr[END_TAG * KTAGS + tid];
    __syncthreads();

    if (tid == 0) {
        int bt_ = 0; float best = term[0];
        for (int k = 1; k < KTAGS; k++)
            if (term[k] > best) { best = term[k]; bt_ = k; }
        out[b] = best;
        float* path = out + BB + (size_t)b * (TT + 1);
        path[TT] = (float)bt_;
        int cur = bt_;
        for (int t = TT - 1; t >= 0; t--) {
            int src = t - (TT - len);
            if (src >= 0) cur = bp[src][cur];
            else          cur = KTAGS;
            path[t] = (float)cur;
        }
    }
}

// ---------------------------------------------------------------------------
extern "C" void kernel_launch(void* const* d_in, const int* in_sizes, int n_in,
                              void* d_out, int out_size, void* d_ws, size_t ws_size,
                              hipStream_t stream) {
    const int*   sentence = (const int*)d_in[0];
    const int*   lengths  = (const int*)d_in[1];
    const float* emb      = (const float*)d_in[2];
    const float* Wf_ih    = (const float*)d_in[3];
    const float* Wf_hh    = (const float*)d_in[4];
    const float* bf_ih    = (const float*)d_in[5];
    const float* bf_hh    = (const float*)d_in[6];
    const float* Wb_ih    = (const float*)d_in[7];
    const float* Wb_hh    = (const float*)d_in[8];
    const float* bb_ih    = (const float*)d_in[9];
    const float* bb_hh    = (const float*)d_in[10];
    const float* Wout     = (const float*)d_in[11];
    const float* bout     = (const float*)d_in[12];
    const float* trans    = (const float*)d_in[13];
    float* out = (float*)d_out;

    // workspace layout
    float* hping = (float*)d_ws;                                 // 3*32768 floats (384KB)
    float* hbuf  = (float*)((char*)d_ws + 3 * SLOTBYTES);        // 2*32*256*512 floats
    float* feats = hbuf + (size_t)2 * BB * TT * HID;             // 32*256*20

    // slot 0 = h(0) = 0.0 (valid); slots 1,2 = 0xFF = NaN sentinel
    (void)hipMemsetAsync(d_ws, 0, SLOTBYTES, stream);
    (void)hipMemsetAsync((char*)d_ws + SLOTBYTES, 0xFF, 2 * SLOTBYTES, stream);

    hipLaunchKernelGGL(k_lstm_persist, dim3(256), dim3(512), 0, stream,
                       lengths, sentence, emb, Wf_hh, Wb_hh, Wf_ih, Wb_ih,
                       bf_ih, bf_hh, bb_ih, bb_hh, hping, hbuf);
    hipLaunchKernelGGL(k_feats, dim3(BB * TT / 4), dim3(256), 0, stream,
                       lengths, hbuf, Wout, bout, feats);
    hipLaunchKernelGGL(k_viterbi, dim3(BB), dim3(64), 0, stream,
                       lengths, trans, feats, out);
}

// Round 7
// 1788.305 us; speedup vs baseline: 1.4794x; 1.4794x over previous
//
#include <hip/hip_runtime.h>
#include <math.h>

#define VOCAB 50000
#define EMB 256
#define HID 512
#define KTAGS 20
#define START_TAG 18
#define END_TAG 19
#define BB 32
#define TT 256
#define NEGV -10000.0f
#define HSROW 644   // 512 phys + skew (4 per 16-float block)
#define XSROW 264   // 256 + 8 skew

__device__ __forceinline__ float sigmoidf_(float x) { return 1.0f / (1.0f + expf(-x)); }

// ---------------------------------------------------------------------------
// K2 r18: DIRECTION-SPLIT persistent LSTM. 512 WGs x 512 thr (2/CU).
//   WG = (dir, 8-unit slice, 8-batch sorted group). Cohort = (dir,grp):
//   64 slice-WGs exchanging h through a 2-parity hping slot, step-barriered.
//
//   Changes vs r16 (2090us) after r17's poll-storm regression (2508us):
//   - REVERT sentinel dataflow; keep r16's narrow-poll protocol shape.
//   - Counter fetch_add arrives (~0.8us/step same-line RMW serialization)
//     -> per-WG FLAG lines: producer does ONE plain relaxed store to its
//     own 64B line; consumer wave0 lane l watches slice l's flag. No RMW,
//     no line ping-pong; polling stays confined to one wave per WG.
//   - Dir-split halves per-WG state (weights 16 VGPR, LDS ~43KB, 2-load
//     staging) so 2 WGs/CU co-reside: one WG's flag-wait overlaps the
//     other's DOTRED -> sync latency hidden by work (VALUBusy 26% -> 40%+).
//   F and B chains are independent; exchange invariant per cohort unchanged:
//   flag==t+1 implies that WG finished step t (incl. its parity reads), so
//   writes of h(t+2) into the same parity slot can never race step-t reads.
// ---------------------------------------------------------------------------
__global__ __launch_bounds__(512, 4) void k_lstm_persist(
    const int* __restrict__ lengths,
    const int* __restrict__ sentence,  // [32][256]
    const float* __restrict__ emb,     // [VOCAB][256]
    const float* __restrict__ Wf_hh, const float* __restrict__ Wb_hh,
    const float* __restrict__ Wf_ih, const float* __restrict__ Wb_ih,
    const float* __restrict__ bf_ih, const float* __restrict__ bf_hh,
    const float* __restrict__ bb_ih, const float* __restrict__ bb_hh,
    float* __restrict__ hping,         // [2 parity][2 dir][32][512]
    unsigned* __restrict__ flags,      // [2 dir][4 grp][64 slice][16 uints]
    float* __restrict__ hbuf)          // [2][32][256][512]
{
    const int wg = blockIdx.x;             // 0..511
    const int dir = wg >> 8;               // 0=F, 1=B
    const int slice = (wg & 255) >> 2;     // unit slice 0..63
    const int grp = wg & 3;                // sorted batch group 0..3
    const int tid = threadIdx.x;
    const int wave = tid >> 6;             // 0..7 = local unit
    const int lane = tid & 63;             // k-slice
    const int u_glob = slice * 8 + wave;   // 0..511

    const float* Whh  = dir ? Wb_hh : Wf_hh;
    const float* WihP = dir ? Wb_ih : Wf_ih;
    const float* bihP = dir ? bb_ih : bf_ih;
    const float* bhhP = dir ? bb_hh : bf_hh;

    // recurrent weights: 8 h-floats per lane per gate (one dir only)
    float4 wD[4][2];
    #pragma unroll
    for (int c = 0; c < 4; c++) {
        const float4* wr = (const float4*)(Whh + (size_t)(c * HID + u_glob) * HID + lane * 8);
        wD[c][0] = wr[0]; wD[c][1] = wr[1];
    }
    // input weights: 4 x-floats per lane per gate
    float4 iD[4];
    #pragma unroll
    for (int c = 0; c < 4; c++)
        iD[c] = *(const float4*)(WihP + (size_t)(c * HID + u_glob) * EMB + lane * 4);
    // biases for this wave's unit
    float bc[4];
    #pragma unroll
    for (int c = 0; c < 4; c++)
        bc[c] = bihP[c * HID + u_glob] + bhhP[c * HID + u_glob];

    __shared__ float hs[8 * HSROW];        // 8 batch rows of h (this dir)
    __shared__ float xs[8 * XSROW];        // 8 batch rows of x (this dir)
    __shared__ float zw[8 * 132];          // [wave][gate*33 + j]
    __shared__ int stok[8][TT];            // tokens for group's 8 sorted batches
    __shared__ int lens_raw[32];
    __shared__ int order_s[32];
    __shared__ int lens_s[32];
    __shared__ int nbt_s[TT];

    if (tid < 32) lens_raw[tid] = lengths[tid];
    __syncthreads();
    if (tid < 32) {
        int me = lens_raw[tid], rank = 0;
        #pragma unroll 4
        for (int o = 0; o < 32; o++) {
            int lo = lens_raw[o];
            rank += (lo > me || (lo == me && o < tid)) ? 1 : 0;
        }
        order_s[rank] = tid;
        lens_s[rank] = me;
    }
    if (tid >= 256) {
        int t = tid - 256, c = 0;
        #pragma unroll 4
        for (int b = 0; b < 32; b++) c += (lens_raw[b] > t) ? 1 : 0;
        nbt_s[t] = c;
    }
    __syncthreads();
    for (int i = tid; i < 8 * TT; i += 512) {
        int j = i >> 8, c = i & 255;
        stok[j][c] = sentence[order_s[grp * 8 + j] * TT + c];
    }
    __syncthreads();

    const int tlimit = lens_s[grp * 8];

    // gate identity: lanes 0..7 = local sorted pos within group
    const int gj = lane & 7;
    const int g_act = (lane < 8);
    const int p_sort = grp * 8 + gj;
    const int mylen = lens_s[p_sort];
    const int mybat = order_s[p_sort];
    float* hout = hbuf + (size_t)(dir * BB + mybat) * TT * HID + u_glob;
    float* hp   = hping + (size_t)dir * BB * HID + (size_t)mybat * HID + u_glob; // parity-0 base

    // h staging: 2 slots/thread. kq = tid&127, rA = tid>>7 (0..3)
    const int kq = tid & 127;
    const int rA = tid >> 7;
    const int wbBase = 4 * kq + 4 * (kq >> 2);
    const int sb_lo = order_s[grp * 8 + rA];
    const int sb_hi = order_s[grp * 8 + rA + 4];
    const int sb0   = order_s[grp * 8];   // longest batch in group: always live
    const size_t o_lo = (size_t)sb_lo * 2048 + (size_t)kq * 16;
    const size_t o_hi = (size_t)sb_hi * 2048 + (size_t)kq * 16;
    const size_t o_fb = (size_t)sb0   * 2048 + (size_t)kq * 16;

    // x staging: row = wave (tid>>6), xpart = tid&63 (4 floats each)
    const int xrow = tid >> 6;
    const int xpart = tid & 63;
    const int xlen = lens_s[grp * 8 + xrow];
    float* xdst = &xs[xrow * XSROW + xpart * 4];

    const int rdoff = 8 * lane + 4 * (lane >> 1);

    float cS = 0.f;
    unsigned* myflag = flags + ((size_t)(dir * 4 + grp) * 64 + slice) * 16;
    const unsigned* pollbase = flags + (size_t)(dir * 4 + grp) * 64 * 16;

#define DOTRED()                                                               \
    for (int j = 0; j < jmax; j++) {                                           \
        const float* hb = &hs[j * HSROW + rdoff];                              \
        float4 h0 = *(const float4*)(hb);                                      \
        float4 h1 = *(const float4*)(hb + 4);                                  \
        float4 xv = *(const float4*)&xs[j * XSROW + lane * 4];                 \
        float a0 = 0.f, a1 = 0.f, a2 = 0.f, a3 = 0.f;                          \
        a0 = fmaf(wD[0][0].x, h0.x, a0); a0 = fmaf(wD[0][0].y, h0.y, a0);      \
        a0 = fmaf(wD[0][0].z, h0.z, a0); a0 = fmaf(wD[0][0].w, h0.w, a0);      \
        a0 = fmaf(wD[0][1].x, h1.x, a0); a0 = fmaf(wD[0][1].y, h1.y, a0);      \
        a0 = fmaf(wD[0][1].z, h1.z, a0); a0 = fmaf(wD[0][1].w, h1.w, a0);      \
        a0 = fmaf(iD[0].x, xv.x, a0);    a0 = fmaf(iD[0].y, xv.y, a0);         \
        a0 = fmaf(iD[0].z, xv.z, a0);    a0 = fmaf(iD[0].w, xv.w, a0);         \
        a1 = fmaf(wD[1][0].x, h0.x, a1); a1 = fmaf(wD[1][0].y, h0.y, a1);      \
        a1 = fmaf(wD[1][0].z, h0.z, a1); a1 = fmaf(wD[1][0].w, h0.w, a1);      \
        a1 = fmaf(wD[1][1].x, h1.x, a1); a1 = fmaf(wD[1][1].y, h1.y, a1);      \
        a1 = fmaf(wD[1][1].z, h1.z, a1); a1 = fmaf(wD[1][1].w, h1.w, a1);      \
        a1 = fmaf(iD[1].x, xv.x, a1);    a1 = fmaf(iD[1].y, xv.y, a1);         \
        a1 = fmaf(iD[1].z, xv.z, a1);    a1 = fmaf(iD[1].w, xv.w, a1);         \
        a2 = fmaf(wD[2][0].x, h0.x, a2); a2 = fmaf(wD[2][0].y, h0.y, a2);      \
        a2 = fmaf(wD[2][0].z, h0.z, a2); a2 = fmaf(wD[2][0].w, h0.w, a2);      \
        a2 = fmaf(wD[2][1].x, h1.x, a2); a2 = fmaf(wD[2][1].y, h1.y, a2);      \
        a2 = fmaf(wD[2][1].z, h1.z, a2); a2 = fmaf(wD[2][1].w, h1.w, a2);      \
        a2 = fmaf(iD[2].x, xv.x, a2);    a2 = fmaf(iD[2].y, xv.y, a2);         \
        a2 = fmaf(iD[2].z, xv.z, a2);    a2 = fmaf(iD[2].w, xv.w, a2);         \
        a3 = fmaf(wD[3][0].x, h0.x, a3); a3 = fmaf(wD[3][0].y, h0.y, a3);      \
        a3 = fmaf(wD[3][0].z, h0.z, a3); a3 = fmaf(wD[3][0].w, h0.w, a3);      \
        a3 = fmaf(wD[3][1].x, h1.x, a3); a3 = fmaf(wD[3][1].y, h1.y, a3);      \
        a3 = fmaf(wD[3][1].z, h1.z, a3); a3 = fmaf(wD[3][1].w, h1.w, a3);      \
        a3 = fmaf(iD[3].x, xv.x, a3);    a3 = fmaf(iD[3].y, xv.y, a3);         \
        a3 = fmaf(iD[3].z, xv.z, a3);    a3 = fmaf(iD[3].w, xv.w, a3);         \
        bool lo32 = (lane & 32) == 0;                                          \
        float tA = __shfl_xor(lo32 ? a2 : a0, 32);                             \
        float tB = __shfl_xor(lo32 ? a3 : a1, 32);                             \
        float rAq = (lo32 ? a0 : a2) + tA;                                     \
        float rBq = (lo32 ? a1 : a3) + tB;                                     \
        bool lo16 = (lane & 16) == 0;                                          \
        float tC = __shfl_xor(lo16 ? rBq : rAq, 16);                           \
        float r  = (lo16 ? rAq : rBq) + tC;                                    \
        r += __shfl_xor(r, 8);                                                 \
        r += __shfl_xor(r, 4);                                                 \
        r += __shfl_xor(r, 2);                                                 \
        r += __shfl_xor(r, 1);                                                 \
        if ((lane & 15) == 0)                                                  \
            zw[wave * 132 + (lane >> 4) * 33 + j] = r;                         \
    }

    for (int t = 0; t < tlimit; t++) {
        const int nbt = nbt_s[t];
        const int jmax = min(max(nbt - grp * 8, 0), 8);
        const int act = g_act && (t < mylen);
        const int pred_lo = (grp * 8 + rA < nbt);
        const int pred_hi = (grp * 8 + rA + 4 < nbt);

        // ---- prefetch x row (barrier-independent; consumed after staging) --
        int posx = dir ? ((t < xlen) ? xlen - 1 - t : t) : t;
        const float* xr = emb + (size_t)stok[xrow][posx] * EMB + xpart * 4;
        float4 xa = *(const float4*)xr;

        // ---- flag wait: wave0 only; lane l watches slice l's flag line ----
        if (t > 0 && wave == 0) {
            const unsigned tgt = (unsigned)t;
            const unsigned* cp = pollbase + lane * 16;
            bool mydone = false;
            while (true) {
                if (!mydone)
                    mydone = __hip_atomic_load(cp, __ATOMIC_RELAXED,
                                               __HIP_MEMORY_SCOPE_AGENT) >= tgt;
                if (__ballot(mydone) == ~0ull) break;
                __builtin_amdgcn_s_sleep(1);
            }
        }
        __syncthreads();

        // ---- stage h(t): 2 sc1 dwordx4 loads, one vmcnt; plus x ----
        {
            const char* baseD = (const char*)hping
                + ((size_t)(t & 1) * 2 * BB * HID + (size_t)dir * BB * HID) * 4;
            const char* fb = baseD + o_fb;
            const char* a0 = pred_lo ? baseD + o_lo : fb;
            const char* a1 = pred_hi ? baseD + o_hi : fb;
            float4 u0, u1;
            asm volatile(
                "global_load_dwordx4 %0, %2, off sc0 sc1\n\t"
                "global_load_dwordx4 %1, %3, off sc0 sc1\n\t"
                "s_waitcnt vmcnt(0)"
                : "=&v"(u0), "=&v"(u1)
                : "v"(a0), "v"(a1)
                : "memory");
            *(float4*)&hs[(rA    ) * HSROW + wbBase] = u0;
            *(float4*)&hs[(rA + 4) * HSROW + wbBase] = u1;
            *(float4*)xdst = xa;
        }
        __syncthreads();

        // ---- dot: Whh.h + Wih.x fused (one dir) ----
        DOTRED();

        // ---- gates; exchange (hping) store only ----
        float hn = 0.f;
        if (act) {
            float iv = zw[wave * 132 +  0 + gj] + bc[0];
            float fv = zw[wave * 132 + 33 + gj] + bc[1];
            float gv = zw[wave * 132 + 66 + gj] + bc[2];
            float ov = zw[wave * 132 + 99 + gj] + bc[3];
            float cn = sigmoidf_(fv) * cS + sigmoidf_(iv) * tanhf(gv);
            hn = sigmoidf_(ov) * tanhf(cn);
            cS = cn;
            __hip_atomic_store(hp + (size_t)(((t + 1) & 1) * 2) * BB * HID, hn,
                               __ATOMIC_RELAXED, __HIP_MEMORY_SCOPE_AGENT);
        }

        // ---- drain exchange stores, then single flag store (no RMW) ----
        __syncthreads();
        if (t < tlimit - 1 && tid == 0)
            __hip_atomic_store(myflag, (unsigned)(t + 1),
                               __ATOMIC_RELAXED, __HIP_MEMORY_SCOPE_AGENT);

        // ---- history store AFTER flag (latency hides in next wait) ----
        if (act) hout[(size_t)t * HID] = hn;
    }
#undef DOTRED
}

// ---------------------------------------------------------------------------
// K3: feats — one wave per (b,t), all 64 lanes, LDS transpose-reduce.
// ---------------------------------------------------------------------------
__global__ __launch_bounds__(256) void k_feats(
    const int* __restrict__ lengths,
    const float* __restrict__ hbuf,  // [2][B][T][512]
    const float* __restrict__ Wout,  // [20][1024]
    const float* __restrict__ bout,  // [20]
    float* __restrict__ feats)       // [B][T][20]
{
    const int w = threadIdx.x >> 6;
    const int lane = threadIdx.x & 63;
    const int idx = blockIdx.x * 4 + w;
    const int b = idx >> 8, t = idx & 255;
    const int len = lengths[b];

    __shared__ float red[4][64][21];

    float acc[KTAGS];
    bool active = (t < len);
    if (active) {
        const int ofs = lane * 16;
        const float* src = (ofs < HID)
            ? hbuf + ((size_t)b * TT + t) * HID + ofs
            : hbuf + ((size_t)(BB + b) * TT + (len - 1 - t)) * HID + (ofs - HID);
        float x[16];
        #pragma unroll
        for (int q = 0; q < 4; q++) {
            float4 v = *(const float4*)(src + 4 * q);
            x[4 * q] = v.x; x[4 * q + 1] = v.y; x[4 * q + 2] = v.z; x[4 * q + 3] = v.w;
        }
        #pragma unroll
        for (int k = 0; k < KTAGS; k++) {
            const float* wr = Wout + (size_t)k * (2 * HID) + ofs;
            float a = 0.f;
            #pragma unroll
            for (int q = 0; q < 4; q++) {
                float4 v = *(const float4*)(wr + 4 * q);
                a = fmaf(x[4 * q], v.x, a);
                a = fmaf(x[4 * q + 1], v.y, a);
                a = fmaf(x[4 * q + 2], v.z, a);
                a = fmaf(x[4 * q + 3], v.w, a);
            }
            acc[k] = a;
        }
    } else {
        #pragma unroll
        for (int k = 0; k < KTAGS; k++) acc[k] = 0.f;
    }
    #pragma unroll
    for (int k = 0; k < KTAGS; k++) red[w][lane][k] = acc[k];
    __syncthreads();

    if (active && lane < KTAGS) {
        float s = bout[lane];
        #pragma unroll 8
        for (int l = 0; l < 64; l++) s += red[w][l][lane];
        feats[(size_t)idx * KTAGS + lane] = s;
    }
}

// ---------------------------------------------------------------------------
// K4: Viterbi — LDS backpointers, double-buffered fv, feats prefetch.
// ---------------------------------------------------------------------------
__global__ __launch_bounds__(64) void k_viterbi(
    const int* __restrict__ lengths,
    const float* __restrict__ trans,  // [20][20]
    const float* __restrict__ feats,  // [B][T][20]
    float* __restrict__ out)          // [32 scores][32*257 path]
{
    const int b = blockIdx.x;
    const int len = lengths[b];
    const int tid = threadIdx.x;

    __shared__ float tr[KTAGS * KTAGS];
    __shared__ float fvb[2][KTAGS];
    __shared__ int   bp[TT][KTAGS];
    __shared__ float term[KTAGS];

    for (int i = tid; i < KTAGS * KTAGS; i += 64) tr[i] = trans[i];
    if (tid < KTAGS) fvb[0][tid] = (tid == START_TAG) ? 0.f : NEGV;
    __syncthreads();

    float ft = (tid < KTAGS) ? feats[((size_t)b * TT) * KTAGS + tid] : 0.f;
    for (int t = 0; t < len; t++) {
        float ftn = (tid < KTAGS && t + 1 < len)
                  ? feats[((size_t)b * TT + t + 1) * KTAGS + tid] : 0.f;
        if (tid < KTAGS) {
            const float* fvc = fvb[t & 1];
            float best = -1e30f; int bi = 0;
            #pragma unroll
            for (int p = 0; p < KTAGS; p++) {
                float s = fvc[p] + tr[tid * KTAGS + p];
                if (s > best) { best = s; bi = p; }
            }
            fvb[(t + 1) & 1][tid] = best + ft;
            bp[t][tid] = bi;
        }
        ft = ftn;
        __syncthreads();
    }

    if (tid < KTAGS) term[tid] = fvb[len & 1][tid] + tr[END_TAG * KTAGS + tid];
    __syncthreads();

    if (tid == 0) {
        int bt_ = 0; float best = term[0];
        for (int k = 1; k < KTAGS; k++)
            if (term[k] > best) { best = term[k]; bt_ = k; }
        out[b] = best;
        float* path = out + BB + (size_t)b * (TT + 1);
        path[TT] = (float)bt_;
        int cur = bt_;
        for (int t = TT - 1; t >= 0; t--) {
            int src = t - (TT - len);
            if (src >= 0) cur = bp[src][cur];
            else          cur = KTAGS;
            path[t] = (float)cur;
        }
    }
}

// ---------------------------------------------------------------------------
extern "C" void kernel_launch(void* const* d_in, const int* in_sizes, int n_in,
                              void* d_out, int out_size, void* d_ws, size_t ws_size,
                              hipStream_t stream) {
    const int*   sentence = (const int*)d_in[0];
    const int*   lengths  = (const int*)d_in[1];
    const float* emb      = (const float*)d_in[2];
    const float* Wf_ih    = (const float*)d_in[3];
    const float* Wf_hh    = (const float*)d_in[4];
    const float* bf_ih    = (const float*)d_in[5];
    const float* bf_hh    = (const float*)d_in[6];
    const float* Wb_ih    = (const float*)d_in[7];
    const float* Wb_hh    = (const float*)d_in[8];
    const float* bb_ih    = (const float*)d_in[9];
    const float* bb_hh    = (const float*)d_in[10];
    const float* Wout     = (const float*)d_in[11];
    const float* bout     = (const float*)d_in[12];
    const float* trans    = (const float*)d_in[13];
    float* out = (float*)d_out;

    // workspace layout
    float*    hping = (float*)d_ws;                              // 65536 floats (256KB)
    unsigned* flags = (unsigned*)((char*)d_ws + 262144);         // 32KB (512 x 64B lines)
    float*    hbuf  = (float*)((char*)d_ws + 262144 + 32768);    // 2*32*256*512 floats
    float*    feats = hbuf + (size_t)2 * BB * TT * HID;          // 32*256*20

    (void)hipMemsetAsync(d_ws, 0, 262144 + 32768, stream);

    hipLaunchKernelGGL(k_lstm_persist, dim3(512), dim3(512), 0, stream,
                       lengths, sentence, emb, Wf_hh, Wb_hh, Wf_ih, Wb_ih,
                       bf_ih, bf_hh, bb_ih, bb_hh, hping, flags, hbuf);
    hipLaunchKernelGGL(k_feats, dim3(BB * TT / 4), dim3(256), 0, stream,
                       lengths, hbuf, Wout, bout, feats);
    hipLaunchKernelGGL(k_viterbi, dim3(BB), dim3(64), 0, stream,
                       lengths, trans, feats, out);
}